// Round 1
// baseline (220.461 us; speedup 1.0000x reference)
//
#include <hip/hip_runtime.h>

#define KDIM 1024
#define NSTEPS 32   // KDIM / BK, BK = 32

typedef __attribute__((ext_vector_type(8))) short bf16x8;
typedef __attribute__((ext_vector_type(4))) short short4v;
typedef __attribute__((ext_vector_type(4))) float f32x4;

__device__ __forceinline__ short f2bf(float f) {
    union { float f; unsigned u; } x; x.f = f;
    unsigned r = x.u + 0x7fffu + ((x.u >> 16) & 1u);   // RNE
    return (short)(r >> 16);
}

// GEMM: C[m][n] = sum_k A[m][k] * W[n][k]  (+bias), M=256 fixed, K=1024 fixed.
// A is bf16 in pre-fragmented layout: elem (m,k) at ((mf*32+kf)*64 + g*16 + r)*8 + e
//   mf=m>>4, r=m&15, kf=k>>5, g=(k>>3)&3, e=k&7.
// W is fp32 [N][1024] row-major, converted to bf16 during LDS staging.
// Block: 256 thr (4 waves as 2M x 2N), tile 256 x BN, BK=32, double-buffered LDS.
template<int BN, bool PRED>
__launch_bounds__(256, 3)
__global__ void gemm_bf16(const short* __restrict__ A0, const float* __restrict__ W0,
                          float* __restrict__ C0, int nb0,
                          const short* __restrict__ A1, const float* __restrict__ W1,
                          float* __restrict__ C1,
                          const float* __restrict__ bias, int N, int ldc)
{
    constexpr int NF = BN / 32;        // n-frags per wave (2 wave columns)
    constexpr int NFRAG = BN / 16;     // n-frags per block
    constexpr int E = BN / 8;          // fp32 elems staged per thread per K-step
    __shared__ short Blds[2][NFRAG * 64 * 8];

    const short* A; const float* W; float* C;
    int n0;
    const int bx = blockIdx.x;
    if (bx < nb0) { A = A0; W = W0; C = C0; n0 = bx * BN; }
    else          { A = A1; W = W1; C = C1; n0 = (bx - nb0) * BN; }

    const int t = threadIdx.x;
    const int lane = t & 63;
    const int wid = t >> 6;
    const int wr = wid >> 1;   // wave row: 0..1 (128 rows each)
    const int wc = wid & 1;    // wave col

    f32x4 acc[8][NF];
    #pragma unroll
    for (int i = 0; i < 8; ++i)
        #pragma unroll
        for (int j = 0; j < NF; ++j)
            acc[i][j] = (f32x4){0.f, 0.f, 0.f, 0.f};

    // staging address precompute: thread covers tile-flat elems [t*E, t*E+E)
    const float* wrow[E / 4];
    int slotoff[E / 4];
    #pragma unroll
    for (int c = 0; c < E / 4; ++c) {
        int flat = t * E + c * 4;
        int n_l = flat >> 5;          // tile row (n)
        int kk  = flat & 31;          // k within step
        int ng  = n0 + n_l;
        if (PRED) ng = (ng < N) ? ng : (N - 1);
        wrow[c] = W + (size_t)ng * KDIM + kk;
        slotoff[c] = ((n_l >> 4) * 64 + (kk >> 3) * 16 + (n_l & 15)) * 8 + (kk & 7);
    }

    auto stage = [&](int s, int buf) {
        #pragma unroll
        for (int c = 0; c < E / 4; ++c) {
            f32x4 v = *(const f32x4*)(wrow[c] + s * 32);
            short4v b;
            b.x = f2bf(v.x); b.y = f2bf(v.y); b.z = f2bf(v.z); b.w = f2bf(v.w);
            *(short4v*)(&Blds[buf][slotoff[c]]) = b;
        }
    };

    stage(0, 0);
    __syncthreads();

    #pragma unroll 2
    for (int s = 0; s < NSTEPS; ++s) {
        const int buf = s & 1;
        if (s + 1 < NSTEPS) stage(s + 1, buf ^ 1);

        bf16x8 bfr[NF];
        #pragma unroll
        for (int nf = 0; nf < NF; ++nf) {
            int nf_g = wc * NF + nf;
            bfr[nf] = *(const bf16x8*)(&Blds[buf][(nf_g * 64 + lane) * 8]);
        }
        #pragma unroll
        for (int mf = 0; mf < 8; ++mf) {
            int mf_g = wr * 8 + mf;
            bf16x8 a = *(const bf16x8*)(A + (size_t)((mf_g * 32 + s) * 64 + lane) * 8);
            #pragma unroll
            for (int nf = 0; nf < NF; ++nf)
                acc[mf][nf] = __builtin_amdgcn_mfma_f32_16x16x32_bf16(a, bfr[nf], acc[mf][nf], 0, 0, 0);
        }
        __syncthreads();
    }

    // epilogue: C/D layout col = lane&15, row = (lane>>4)*4 + reg
    #pragma unroll
    for (int mf = 0; mf < 8; ++mf) {
        int row = wr * 128 + mf * 16 + ((lane >> 4) << 2);
        #pragma unroll
        for (int nf = 0; nf < NF; ++nf) {
            int col = n0 + (wc * NF + nf) * 16 + (lane & 15);
            if (PRED && col >= N) continue;
            float bv = bias ? bias[col] : 0.0f;
            #pragma unroll
            for (int r = 0; r < 4; ++r)
                C[(size_t)(row + r) * ldc + col] = acc[mf][nf][r] + bv;
        }
    }
}

// Gather embedding row / convert hidden rows into bf16 fragment layout.
__global__ void prep_kernel(const int* __restrict__ ids, const float* __restrict__ hidden,
                            const float* __restrict__ emb,
                            short* __restrict__ x_frag, short* __restrict__ h_frag)
{
    const int m = blockIdx.x;        // 0..255
    const int which = blockIdx.y;    // 0: emb gather -> x, 1/2: hidden layer
    const int j = threadIdx.x << 3;  // 128 threads * 8 elems

    const float* src;
    short* dst;
    if (which == 0) { src = emb + (size_t)ids[m] * KDIM; dst = x_frag; }
    else {
        src = hidden + ((size_t)(which - 1) * 256 + m) * KDIM;
        dst = h_frag + (size_t)(which - 1) * 256 * KDIM;
    }
    f32x4 v0 = *(const f32x4*)(src + j);
    f32x4 v1 = *(const f32x4*)(src + j + 4);
    int mf = m >> 4, rr = m & 15, kf = j >> 5, g = (j >> 3) & 3;
    short* p = dst + (size_t)((mf * 32 + kf) * 64 + g * 16 + rr) * 8;
    short4v a, b;
    a.x = f2bf(v0.x); a.y = f2bf(v0.y); a.z = f2bf(v0.z); a.w = f2bf(v0.w);
    b.x = f2bf(v1.x); b.y = f2bf(v1.y); b.z = f2bf(v1.z); b.w = f2bf(v1.w);
    *(short4v*)p = a;
    *(short4v*)(p + 4) = b;
}

// GRU gates: h_new = (1-z)*n + z*h ; writes fp32 hidden_out and bf16 x fragments.
__global__ void gate_kernel(const float* __restrict__ gi, const float* __restrict__ gh,
                            const float* __restrict__ bi, const float* __restrict__ bh,
                            const float* __restrict__ hprev, float* __restrict__ hout,
                            short* __restrict__ x_frag)
{
    const int m = blockIdx.x;
    const int j = threadIdx.x << 3;
    const float* gim = gi + (size_t)m * 3072;
    const float* ghm = gh + (size_t)m * 3072;
    const float* hp = hprev + (size_t)m * KDIM;
    float* ho = hout + (size_t)m * KDIM;
    int mf = m >> 4, rr = m & 15, kf = j >> 5, g = (j >> 3) & 3;
    short* xp = x_frag + (size_t)((mf * 32 + kf) * 64 + g * 16 + rr) * 8;

    #pragma unroll
    for (int half = 0; half < 2; ++half) {
        int jj = j + half * 4;
        f32x4 vir = *(const f32x4*)(gim + jj);
        f32x4 viz = *(const f32x4*)(gim + 1024 + jj);
        f32x4 vin = *(const f32x4*)(gim + 2048 + jj);
        f32x4 vhr = *(const f32x4*)(ghm + jj);
        f32x4 vhz = *(const f32x4*)(ghm + 1024 + jj);
        f32x4 vhn = *(const f32x4*)(ghm + 2048 + jj);
        f32x4 bir = *(const f32x4*)(bi + jj);
        f32x4 biz = *(const f32x4*)(bi + 1024 + jj);
        f32x4 bin = *(const f32x4*)(bi + 2048 + jj);
        f32x4 bhr = *(const f32x4*)(bh + jj);
        f32x4 bhz = *(const f32x4*)(bh + 1024 + jj);
        f32x4 bhn = *(const f32x4*)(bh + 2048 + jj);
        f32x4 vh  = *(const f32x4*)(hp + jj);
        f32x4 outv;
        short4v xb;
        #pragma unroll
        for (int e = 0; e < 4; ++e) {
            float r = 1.f / (1.f + __expf(-(vir[e] + bir[e] + vhr[e] + bhr[e])));
            float z = 1.f / (1.f + __expf(-(viz[e] + biz[e] + vhz[e] + bhz[e])));
            float n = tanhf(vin[e] + bin[e] + r * (vhn[e] + bhn[e]));
            outv[e] = (1.f - z) * n + z * vh[e];
        }
        *(f32x4*)(ho + jj) = outv;
        xb.x = f2bf(outv[0]); xb.y = f2bf(outv[1]); xb.z = f2bf(outv[2]); xb.w = f2bf(outv[3]);
        *(short4v*)(xp + half * 4) = xb;
    }
}

extern "C" void kernel_launch(void* const* d_in, const int* in_sizes, int n_in,
                              void* d_out, int out_size, void* d_ws, size_t ws_size,
                              hipStream_t stream)
{
    const int*   ids    = (const int*)d_in[0];
    const float* hidden = (const float*)d_in[1];
    const float* emb    = (const float*)d_in[2];
    const float* w_ih   = (const float*)d_in[3];
    const float* w_hh   = (const float*)d_in[4];
    const float* b_ih   = (const float*)d_in[5];
    const float* b_hh   = (const float*)d_in[6];
    const float* dec_w  = (const float*)d_in[7];
    const float* dec_b  = (const float*)d_in[8];

    float* out = (float*)d_out;
    float* logits = out;                                  // [256][50000]
    float* hidden_out = out + (size_t)256 * 50000;        // [2][256][1024]

    short* x_frag = (short*)d_ws;                         // 256*1024 bf16
    short* h_frag = x_frag + 256 * 1024;                  // 2*256*1024 bf16
    // gi/gh scratch lives in the (not yet written) logits region of d_out
    float* gi = logits;                                   // 256*3072
    float* gh = logits + (size_t)256 * 3072;              // 256*3072

    prep_kernel<<<dim3(256, 3), 128, 0, stream>>>(ids, hidden, emb, x_frag, h_frag);

    for (int l = 0; l < 2; ++l) {
        gemm_bf16<32, false><<<192, 256, 0, stream>>>(
            x_frag, w_ih + (size_t)l * 3072 * 1024, gi, 96,
            h_frag + (size_t)l * 256 * 1024, w_hh + (size_t)l * 3072 * 1024, gh,
            nullptr, 3072, 3072);
        gate_kernel<<<256, 128, 0, stream>>>(
            gi, gh, b_ih + (size_t)l * 3072, b_hh + (size_t)l * 3072,
            hidden + (size_t)l * 256 * 1024,
            hidden_out + (size_t)l * 256 * 1024, x_frag);
    }

    gemm_bf16<64, true><<<782, 256, 0, stream>>>(
        x_frag, dec_w, logits, 782,
        x_frag, dec_w, logits,
        dec_b, 50000, 50000);
}